// Round 9
// baseline (692.040 us; speedup 1.0000x reference)
//
#include <hip/hip_runtime.h>
#include <math.h>

#define N_NODES 100000
#define N_EDGES 1600000
#define NCLS_ 40
#define NSCAN_BLOCKS ((N_NODES + 1023) / 1024)   // 98
#define SRCS_PAD (N_EDGES + 3 * N_NODES + 64)     // 4-aligned segments + overread pad

// 1/sqrt(32) * log2(e): folded into Wq/bq so edge pass does exp2(p) directly
#define QSCALE (0.17677669529663687f * 1.4426950408889634f)

#if __has_builtin(__builtin_amdgcn_exp2f)
#define EXP2(x) __builtin_amdgcn_exp2f(x)
#else
#define EXP2(x) exp2f(x)
#endif

typedef short bf16x8 __attribute__((ext_vector_type(8)));
typedef float f32x4 __attribute__((ext_vector_type(4)));

// bf16 helpers (RNE pack, exact unpack)
__device__ __forceinline__ unsigned short f2b(float f) {
    union { float f; unsigned u; } v; v.f = f;
    unsigned r = v.u + 0x7fffu + ((v.u >> 16) & 1u);
    return (unsigned short)(r >> 16);
}
// HW packed f32->bf16 (RNE), 1 inst instead of ~9 VALU; low=x, high=y
__device__ __forceinline__ unsigned cvtpk(float x, float y) {
    unsigned r;
    asm("v_cvt_pk_bf16_f32 %0, %1, %2" : "=v"(r) : "v"(x), "v"(y));
    return r;
}
__device__ __forceinline__ float2 up2(unsigned u) {   // packed pair -> floats
    union { unsigned u; float f; } a, b;
    a.u = u << 16; b.u = u & 0xffff0000u;
    return make_float2(a.f, b.f);
}
__device__ __forceinline__ float b2f(unsigned short s) {
    union { unsigned u; float f; } v; v.u = ((unsigned)s) << 16;
    return v.f;
}

// qkvs row layout (512 shorts):
//   [0,128)    Q (pre-scaled by 1/sqrt(32)*log2e), channel c at c
//   [128,384)  K/V interleaved 16B/lane: half-lane hl (0..31) owns shorts
//              128+8hl..128+8hl+7 = {K4hl..K4hl+3, V4hl..V4hl+3}
//   [384,512)  S (skip), channel c at 384+c

// ---------------------------------------------------------------- W preconvert + deg zero (merged)
// blocks [0,512): fp32 W -> bf16 FRAGMENT-STREAM layout
//   per (l, mat, ghalf): [c][ks][lane][8], lane=(quad<<4)|ln,
//   channel(col) = ghalf*64 + (ln>>2)*16 + c*4 + (ln&3),  k = ks*32+quad*8+j
// blocks [512, 512+391): zero deg[N_NODES]
__global__ __launch_bounds__(256) void wconv_zero_kernel(
    const float* __restrict__ Wq, const float* __restrict__ Wk,
    const float* __restrict__ Wv, const float* __restrict__ Ws,
    unsigned short* __restrict__ Wbf, int* __restrict__ deg) {
    int b = blockIdx.x;
    if (b >= 512) {
        int i = (b - 512) * 256 + threadIdx.x;
        if (i < N_NODES) deg[i] = 0;
        return;
    }
    int tid = b * 256 + threadIdx.x;
    int j     = tid & 7;
    int lane  = (tid >> 3) & 63;
    int ks    = (tid >> 9) & 3;
    int c     = (tid >> 11) & 3;
    int ghalf = (tid >> 13) & 1;
    int mat   = (tid >> 14) & 3;
    int l     = tid >> 16;
    int ln = lane & 15, quad = lane >> 4;
    int col = ghalf * 64 + ((ln >> 2) << 4) + (c << 2) + (ln & 3);
    int krow = (ks << 5) + (quad << 3) + j;
    const float* W = (mat == 0) ? Wq : (mat == 1) ? Wk : (mat == 2) ? Wv : Ws;
    float w = W[l * 16384 + krow * 128 + col];
    if (mat == 0) w *= QSCALE;
    Wbf[tid] = f2b(w);
}

// ---------------------------------------------------------------- CSR build
// single pass (R8 had 8x replicated reads of the edge list)
__global__ __launch_bounds__(256) void hist_kernel(
    const int* __restrict__ dst, int* __restrict__ deg) {
    int stride = gridDim.x * 256;
    for (int i = blockIdx.x * 256 + threadIdx.x; i < N_EDGES; i += stride)
        atomicAdd(&deg[dst[i]], 1);
}

// exclusive scan of PADDED degrees ((deg+3)&~3) so each node's segment start
// is 4-aligned -> int4 source loads in the edge pass.
__global__ __launch_bounds__(1024) void scan_block_kernel(
    const int* __restrict__ deg, int* __restrict__ rowptr, int* __restrict__ sums) {
    __shared__ int tmp[1024];
    int t = threadIdx.x;
    int i = blockIdx.x * 1024 + t;
    int v = (i < N_NODES) ? ((deg[i] + 3) & ~3) : 0;
    tmp[t] = v;
    __syncthreads();
    for (int d = 1; d < 1024; d <<= 1) {
        int add = (t >= d) ? tmp[t - d] : 0;
        __syncthreads();
        tmp[t] += add;
        __syncthreads();
    }
    if (i < N_NODES) rowptr[i] = tmp[t] - v;
    if (t == 1023) sums[blockIdx.x] = tmp[1023];
}

// adds the cross-chunk prefix (computed inline from raw per-chunk sums — one
// wave-reduce; replaces the separate scan_sums launch), writes cursor, zeroes
// pad slots, and zeroes 16 slack ints past the global padded end (masked-tail
// int4 reads can overshoot the final segment by up to 4 ints).
__global__ __launch_bounds__(256) void scan_add_kernel(
    int* __restrict__ rowptr, const int* __restrict__ sums,
    const int* __restrict__ deg,
    int* __restrict__ cursor, int* __restrict__ srcs) {
    __shared__ int base_s;
    int t = threadIdx.x;
    int limit = blockIdx.x >> 2;           // nodes here are in 1024-chunk (b>>2)
    if (t < 64) {
        int v = (t < limit) ? sums[t] : 0;           // limit <= 97
        int v2 = (t + 64 < limit) ? sums[t + 64] : 0;
        v += v2;
        for (int m = 1; m < 64; m <<= 1) v += __shfl_xor(v, m);
        if (t == 0) base_s = v;
    }
    __syncthreads();
    int base = base_s;
    int i = blockIdx.x * 256 + t;
    if (i < N_NODES) {
        int val = rowptr[i] + base;
        rowptr[i] = val;
        cursor[i] = val;
        int d = deg[i];
        int pad = ((d + 3) & ~3);
        for (int j = d; j < pad; ++j) srcs[val + j] = 0;
        if (i == N_NODES - 1) {
            int end = val + pad;
            for (int j = 0; j < 16; ++j) srcs[end + j] = 0;
        }
    }
}

// stores BYTE offsets of the source node's qkvs row (src*1024); single pass
__global__ __launch_bounds__(256) void scatter_kernel(
    const int* __restrict__ src, const int* __restrict__ dst,
    int* __restrict__ cursor, int* __restrict__ srcs) {
    int stride = gridDim.x * 256;
    for (int i = blockIdx.x * 256 + threadIdx.x; i < N_EDGES; i += stride) {
        int pos = atomicAdd(&cursor[dst[i]], 1);
        srcs[pos] = src[i] << 10;
    }
}

// ---------------------------------------------------------------- QKVS GEMM (bf16 MFMA)
// Operand-swapped mfma(W, X) -> D[channel][node].  W in fragment-stream LDS
// layout [c][ks][lane][8]: staging is a linear 32B/thread copy and every
// ds_read is linear-in-lane => zero bank conflicts.  Channel perm (wconv)
// makes each lane's 16 outputs per group CONTIGUOUS channels.
__global__ __launch_bounds__(512, 4) void gemm_qkvs_kernel(
    const void* __restrict__ Ap, int a_is_bf16,
    const unsigned short* __restrict__ Wbf,   // this layer: [mat][ghalf][c][ks][lane][8]
    const float* __restrict__ b0, const float* __restrict__ b1,
    const float* __restrict__ b2, const float* __restrict__ b3,
    unsigned short* __restrict__ out) {
    __shared__ unsigned short WL[2][8192];
    int t = threadIdx.x;
    int row0 = blockIdx.x * 128;
    int wr = t >> 6, lane = t & 63;
    int ln = lane & 15, quad = lane >> 4;
    int node = row0 + wr * 16 + ln;
    int nodeC = (node < N_NODES) ? node : (N_NODES - 1);

    // A fragments: B-operand lane(ln,quad) = A[node][ks*32+quad*8 .. +7]
    bf16x8 aF[4];
    if (a_is_bf16) {
        const unsigned short* ar = (const unsigned short*)Ap + (size_t)nodeC * 128;
        #pragma unroll
        for (int ks = 0; ks < 4; ++ks)
            aF[ks] = *(const bf16x8*)&ar[ks * 32 + quad * 8];
    } else {
        const float* ar = (const float*)Ap + (size_t)nodeC * 128;
        #pragma unroll
        for (int ks = 0; ks < 4; ++ks) {
            float4 f0 = *(const float4*)&ar[ks * 32 + quad * 8];
            float4 f1 = *(const float4*)&ar[ks * 32 + quad * 8 + 4];
            union { unsigned u[4]; bf16x8 v; } cv;
            cv.u[0] = cvtpk(f0.x, f0.y);
            cv.u[1] = cvtpk(f0.z, f0.w);
            cv.u[2] = cvtpk(f1.x, f1.y);
            cv.u[3] = cvtpk(f1.z, f1.w);
            aF[ks] = cv.v;
        }
    }

    // stage g=0: linear copy, 32B/thread
    {
        const uint4* Wg4 = (const uint4*)Wbf;
        uint4 a = Wg4[t * 2], b = Wg4[t * 2 + 1];
        uint4* d4 = (uint4*)WL[0] + t * 2;
        d4[0] = a; d4[1] = b;
    }
    __syncthreads();

    bool ok = node < N_NODES;
    #pragma unroll
    for (int g = 0; g < 8; ++g) {
        int mat = g >> 1;
        int cur = g & 1;
        const float* bias = (mat == 0) ? b0 : (mat == 1) ? b1 : (mat == 2) ? b2 : b3;
        int cb = (g & 1) * 64;

        uint4 pfa, pfb;
        if (g < 7) {
            const uint4* Wg4 = (const uint4*)(Wbf + (size_t)(g + 1) * 8192);
            pfa = Wg4[t * 2]; pfb = Wg4[t * 2 + 1];
        }

        f32x4 acc[4];
        #pragma unroll
        for (int c = 0; c < 4; ++c) acc[c] = (f32x4){0.f, 0.f, 0.f, 0.f};
        #pragma unroll
        for (int ks = 0; ks < 4; ++ks) {
            #pragma unroll
            for (int c = 0; c < 4; ++c) {
                bf16x8 w = *(bf16x8*)&WL[cur][((c * 4 + ks) * 64 + lane) * 8];
                acc[c] = __builtin_amdgcn_mfma_f32_16x16x32_bf16(w, aF[ks], acc[c], 0, 0, 0);
            }
        }

        // epilogue: lane holds 16 CONTIGUOUS channels cb+quad*16 .. +15 of node
        if (ok) {
            float s = (mat == 0) ? QSCALE : 1.0f;
            float v[16];
            #pragma unroll
            for (int c = 0; c < 4; ++c) {
                float4 bb = *(const float4*)&bias[cb + quad * 16 + c * 4];
                v[c * 4 + 0] = acc[c][0] + bb.x * s;
                v[c * 4 + 1] = acc[c][1] + bb.y * s;
                v[c * 4 + 2] = acc[c][2] + bb.z * s;
                v[c * 4 + 3] = acc[c][3] + bb.w * s;
            }
            unsigned pk[8];
            #pragma unroll
            for (int m = 0; m < 8; ++m) pk[m] = cvtpk(v[2 * m], v[2 * m + 1]);
            unsigned short* orow = out + (size_t)node * 512;
            if (mat == 0 || mat == 3) {
                int base = (mat == 0 ? 0 : 384) + cb + quad * 16;
                uint4 w0 = make_uint4(pk[0], pk[1], pk[2], pk[3]);
                uint4 w1 = make_uint4(pk[4], pk[5], pk[6], pk[7]);
                *(uint4*)&orow[base] = w0;
                *(uint4*)&orow[base + 8] = w1;
            } else {
                int boff = (mat == 2) ? 4 : 0;
                #pragma unroll
                for (int c = 0; c < 4; ++c) {
                    int pos = 128 + 8 * ((cb >> 2) + quad * 4 + c) + boff;
                    uint2 wd; wd.x = pk[2 * c]; wd.y = pk[2 * c + 1];
                    *(uint2*)&orow[pos] = wd;
                }
            }
        }

        if (g < 7) {
            uint4* d4 = (uint4*)WL[cur ^ 1] + t * 2;
            d4[0] = pfa; d4[1] = pfb;
        }
        __syncthreads();
    }
}

// ---------------------------------------------------------------- fused edge pass
// HALF-WAVE per edge; 8 edges/wave-iter: each half-lane group handles 4
// CONTIGUOUS edges (srcs pre-scaled to byte offsets; segment starts 4-aligned
// -> one int4 srcs load per iter, software-pipelined; prefetch guarded).
#define EDGE(KV, ECOND) {                                            \
        float2 k01 = up2(KV.x), k23 = up2(KV.y);                     \
        float p = q01.x*k01.x + q01.y*k01.y + q23.x*k23.x + q23.y*k23.y; \
        p += __shfl_xor(p, 1);                                       \
        p += __shfl_xor(p, 2);                                       \
        p += __shfl_xor(p, 4);                                       \
        float e = (ECOND);                                           \
        float2 v01 = up2(KV.z), v23 = up2(KV.w);                     \
        a0 = fmaf(e, v01.x, a0); a1 = fmaf(e, v01.y, a1);            \
        a2 = fmaf(e, v23.x, a2); a3 = fmaf(e, v23.y, a3);            \
        dsum += e; }

__global__ __launch_bounds__(256) void edge_fused_kernel(
    const unsigned short* __restrict__ qkvs,
    const int* __restrict__ srcs, const int* __restrict__ rowptr,
    const int* __restrict__ deg,
    const float* __restrict__ gamma, const float* __restrict__ beta,
    unsigned short* __restrict__ hout) {
    int n = (blockIdx.x * 256 + threadIdx.x) >> 6;
    int lane = threadIdx.x & 63;
    if (n >= N_NODES) return;
    int half = lane >> 5, hl = lane & 31;
    const unsigned short* qrow = qkvs + (size_t)n * 512;
    uint2 qu = *(const uint2*)&qrow[4 * hl];
    float2 q01 = up2(qu.x), q23 = up2(qu.y);
    uint2 su = *(const uint2*)&qrow[384 + 4 * hl];
    float2 sk01 = up2(su.x), sk23 = up2(su.y);
    int e0 = rowptr[n];
    int rem = deg[n];
    const char* kbase = (const char*)qkvs + 256 + 16 * hl;
    const int* sb = srcs + e0 + 4 * half;   // 16B-aligned (e0 % 4 == 0)
    float a0 = 0.f, a1 = 0.f, a2 = 0.f, a3 = 0.f, dsum = 0.f;

    int4 oc;
    if (rem >= 8) oc = *(const int4*)sb;
    while (rem >= 8) {
        int4 on;
        if (rem >= 16) on = *(const int4*)(sb + 8);  // guarded prefetch
        uint4 kv0 = *(const uint4*)(kbase + (unsigned)oc.x);
        uint4 kv1 = *(const uint4*)(kbase + (unsigned)oc.y);
        uint4 kv2 = *(const uint4*)(kbase + (unsigned)oc.z);
        uint4 kv3 = *(const uint4*)(kbase + (unsigned)oc.w);
        EDGE(kv0, EXP2(p));
        EDGE(kv1, EXP2(p));
        EDGE(kv2, EXP2(p));
        EDGE(kv3, EXP2(p));
        oc = on; sb += 8; rem -= 8;
    }
    if (rem > 0) {                                   // one masked pass, rem in 1..7
        int4 ot = *(const int4*)sb;                  // pads+slack zeroed -> safe gather
        int tb = 4 * half;
        uint4 kv0 = *(const uint4*)(kbase + (unsigned)ot.x);
        uint4 kv1 = *(const uint4*)(kbase + (unsigned)ot.y);
        uint4 kv2 = *(const uint4*)(kbase + (unsigned)ot.z);
        uint4 kv3 = *(const uint4*)(kbase + (unsigned)ot.w);
        EDGE(kv0, (tb + 0 < rem) ? EXP2(p) : 0.f);
        EDGE(kv1, (tb + 1 < rem) ? EXP2(p) : 0.f);
        EDGE(kv2, (tb + 2 < rem) ? EXP2(p) : 0.f);
        EDGE(kv3, (tb + 3 < rem) ? EXP2(p) : 0.f);
    }

    // combine halves (lanes l and l+32 hold same channels, different edges)
    a0 += __shfl_xor(a0, 32); a1 += __shfl_xor(a1, 32);
    a2 += __shfl_xor(a2, 32); a3 += __shfl_xor(a3, 32);
    dsum += __shfl_xor(dsum, 32);
    float dinv = 1.0f / (dsum + 1e-16f);
    float o0 = a0 * dinv + sk01.x, o1 = a1 * dinv + sk01.y;
    float o2 = a2 * dinv + sk23.x, o3 = a3 * dinv + sk23.y;
    float sum = o0 + o1 + o2 + o3;
    for (int m = 1; m < 64; m <<= 1) sum += __shfl_xor(sum, m);
    float mu = sum * (1.0f / 256.0f);          // halves duplicated -> /256
    float d0 = o0 - mu, d1 = o1 - mu, d2 = o2 - mu, d3 = o3 - mu;
    float sq = d0 * d0 + d1 * d1 + d2 * d2 + d3 * d3;
    for (int m = 1; m < 64; m <<= 1) sq += __shfl_xor(sq, m);
    float rs = rsqrtf(sq * (1.0f / 256.0f) + 1e-5f);
    if (half == 0) {
        float4 g4 = *(const float4*)&gamma[4 * hl];
        float4 b4 = *(const float4*)&beta[4 * hl];
        float r0 = fmaxf(d0 * rs * g4.x + b4.x, 0.f);
        float r1 = fmaxf(d1 * rs * g4.y + b4.y, 0.f);
        float r2 = fmaxf(d2 * rs * g4.z + b4.z, 0.f);
        float r3 = fmaxf(d3 * rs * g4.w + b4.w, 0.f);
        uint2 w;
        w.x = cvtpk(r0, r1);
        w.y = cvtpk(r2, r3);
        *(uint2*)&hout[(size_t)n * 128 + 4 * hl] = w;
    }
}

// ---------------------------------------------------------------- classifier (h is bf16)
// No LDS: lane = row; FULL h row in 16x uint4 regs; wave = 10-col group so
// Wout/bout addresses are wave-uniform -> scalar loads, FMA-bound.
__global__ __launch_bounds__(256) void out_gemm_kernel(
    const unsigned short* __restrict__ h, const float* __restrict__ Wout,
    const float* __restrict__ bout, float* __restrict__ out) {
    int wv = __builtin_amdgcn_readfirstlane((int)(threadIdx.x >> 6)); // 0..3
    int l = threadIdx.x & 63;
    int n = blockIdx.x * 64 + l;
    int jb = wv * 10;
    int nc = (n < N_NODES) ? n : (N_NODES - 1);
    const unsigned short* hrow = h + (size_t)nc * 128;
    uint4 hp[16];
    #pragma unroll
    for (int i = 0; i < 16; ++i) hp[i] = *(const uint4*)&hrow[i * 8];
    float acc[10];
    #pragma unroll
    for (int j = 0; j < 10; ++j) acc[j] = bout[jb + j];
    #pragma unroll
    for (int i = 0; i < 16; ++i) {   // channel group 8i..8i+7
        float2 c01 = up2(hp[i].x), c23 = up2(hp[i].y);
        float2 c45 = up2(hp[i].z), c67 = up2(hp[i].w);
        float hc0 = c01.x, hc1 = c01.y, hc2 = c23.x, hc3 = c23.y;
        float hc4 = c45.x, hc5 = c45.y, hc6 = c67.x, hc7 = c67.y;
        #pragma unroll
        for (int j = 0; j < 10; ++j) {
            const float* wk = Wout + (i * 8) * NCLS_ + jb + j;
            acc[j] = fmaf(hc0, wk[0 * NCLS_], acc[j]);
            acc[j] = fmaf(hc1, wk[1 * NCLS_], acc[j]);
            acc[j] = fmaf(hc2, wk[2 * NCLS_], acc[j]);
            acc[j] = fmaf(hc3, wk[3 * NCLS_], acc[j]);
            acc[j] = fmaf(hc4, wk[4 * NCLS_], acc[j]);
            acc[j] = fmaf(hc5, wk[5 * NCLS_], acc[j]);
            acc[j] = fmaf(hc6, wk[6 * NCLS_], acc[j]);
            acc[j] = fmaf(hc7, wk[7 * NCLS_], acc[j]);
        }
    }
    if (n < N_NODES) {
        #pragma unroll
        for (int j = 0; j < 10; ++j) out[(size_t)n * NCLS_ + jb + j] = acc[j];
    }
}

// ---------------------------------------------------------------- launch
extern "C" void kernel_launch(void* const* d_in, const int* in_sizes, int n_in,
                              void* d_out, int out_size, void* d_ws, size_t ws_size,
                              hipStream_t stream) {
    const float* x    = (const float*)d_in[0];
    const int*   ei   = (const int*)d_in[1];
    const int*   src  = ei;
    const int*   dst  = ei + N_EDGES;
    const float* Wq   = (const float*)d_in[2];
    const float* bq   = (const float*)d_in[3];
    const float* Wk   = (const float*)d_in[4];
    const float* bk   = (const float*)d_in[5];
    const float* Wv   = (const float*)d_in[6];
    const float* bv   = (const float*)d_in[7];
    const float* Wsk  = (const float*)d_in[8];
    const float* bsk  = (const float*)d_in[9];
    const float* gmm  = (const float*)d_in[10];
    const float* bta  = (const float*)d_in[11];
    const float* Wout = (const float*)d_in[12];
    const float* bout = (const float*)d_in[13];
    float* outp = (float*)d_out;

    char* p = (char*)d_ws;
    auto carve = [&](size_t bytes) {
        char* r = p;
        p += (bytes + 255) & ~(size_t)255;
        return r;
    };
    unsigned short* qkvs = (unsigned short*)carve((size_t)N_NODES * 512 * 2);
    unsigned short* h    = (unsigned short*)carve((size_t)N_NODES * 128 * 2);
    unsigned short* Wbf  = (unsigned short*)carve((size_t)131072 * 2);
    int* deg     = (int*)carve((size_t)N_NODES * 4);
    int* rowptr  = (int*)carve((size_t)(N_NODES + 1) * 4);
    int* cursor  = (int*)carve((size_t)N_NODES * 4);
    int* srcs    = (int*)carve((size_t)SRCS_PAD * 4);
    int* sums    = (int*)carve((size_t)NSCAN_BLOCKS * 4);

    wconv_zero_kernel<<<512 + (N_NODES + 255) / 256, 256, 0, stream>>>(
        Wq, Wk, Wv, Wsk, Wbf, deg);
    hist_kernel<<<2048, 256, 0, stream>>>(dst, deg);
    scan_block_kernel<<<NSCAN_BLOCKS, 1024, 0, stream>>>(deg, rowptr, sums);
    scan_add_kernel<<<(N_NODES + 255) / 256, 256, 0, stream>>>(rowptr, sums, deg, cursor, srcs);
    scatter_kernel<<<2048, 256, 0, stream>>>(src, dst, cursor, srcs);

    for (int l = 0; l < 2; ++l) {
        const void* hin = l ? (const void*)h : (const void*)x;
        gemm_qkvs_kernel<<<(N_NODES + 127) / 128, 512, 0, stream>>>(
            hin, l, Wbf + (size_t)l * 65536,
            bq + l * 128, bk + l * 128, bv + l * 128, bsk + l * 128, qkvs);
        edge_fused_kernel<<<(N_NODES + 3) / 4, 256, 0, stream>>>(
            qkvs, srcs, rowptr, deg, gmm + l * 128, bta + l * 128, h);
    }
    out_gemm_kernel<<<(N_NODES + 63) / 64, 256, 0, stream>>>(h, Wout, bout, outp);
}

// Round 10
// 663.628 us; speedup vs baseline: 1.0428x; 1.0428x over previous
//
#include <hip/hip_runtime.h>
#include <math.h>

#define N_NODES 100000
#define N_EDGES 1600000
#define NCLS_ 40
#define NSCAN_BLOCKS ((N_NODES + 1023) / 1024)   // 98
#define DRANGE 12500                              // N_NODES / 8 XCD groups
#define SRCS_PAD (N_EDGES + 3 * N_NODES + 64)     // 4-aligned segments + overread pad

// 1/sqrt(32) * log2(e): folded into Wq/bq so edge pass does exp2(p) directly
#define QSCALE (0.17677669529663687f * 1.4426950408889634f)

#if __has_builtin(__builtin_amdgcn_exp2f)
#define EXP2(x) __builtin_amdgcn_exp2f(x)
#else
#define EXP2(x) exp2f(x)
#endif

typedef short bf16x8 __attribute__((ext_vector_type(8)));
typedef float f32x4 __attribute__((ext_vector_type(4)));

// bf16 helpers (RNE pack, exact unpack)
__device__ __forceinline__ unsigned short f2b(float f) {
    union { float f; unsigned u; } v; v.f = f;
    unsigned r = v.u + 0x7fffu + ((v.u >> 16) & 1u);
    return (unsigned short)(r >> 16);
}
// HW packed f32->bf16 (RNE), 1 inst instead of ~9 VALU; low=x, high=y
__device__ __forceinline__ unsigned cvtpk(float x, float y) {
    unsigned r;
    asm("v_cvt_pk_bf16_f32 %0, %1, %2" : "=v"(r) : "v"(x), "v"(y));
    return r;
}
__device__ __forceinline__ float2 up2(unsigned u) {   // packed pair -> floats
    union { unsigned u; float f; } a, b;
    a.u = u << 16; b.u = u & 0xffff0000u;
    return make_float2(a.f, b.f);
}
__device__ __forceinline__ float b2f(unsigned short s) {
    union { unsigned u; float f; } v; v.u = ((unsigned)s) << 16;
    return v.f;
}

// qkvs row layout (512 shorts):
//   [0,128)    Q (pre-scaled by 1/sqrt(32)*log2e), channel c at c
//   [128,384)  K/V interleaved 16B/lane: half-lane hl (0..31) owns shorts
//              128+8hl..128+8hl+7 = {K4hl..K4hl+3, V4hl..V4hl+3}
//   [384,512)  S (skip), channel c at 384+c

// ---------------------------------------------------------------- W preconvert + deg zero (merged)
__global__ __launch_bounds__(256) void wconv_zero_kernel(
    const float* __restrict__ Wq, const float* __restrict__ Wk,
    const float* __restrict__ Wv, const float* __restrict__ Ws,
    unsigned short* __restrict__ Wbf, int* __restrict__ deg) {
    int b = blockIdx.x;
    if (b >= 512) {
        int i = (b - 512) * 256 + threadIdx.x;
        if (i < N_NODES) deg[i] = 0;
        return;
    }
    int tid = b * 256 + threadIdx.x;
    int j     = tid & 7;
    int lane  = (tid >> 3) & 63;
    int ks    = (tid >> 9) & 3;
    int c     = (tid >> 11) & 3;
    int ghalf = (tid >> 13) & 1;
    int mat   = (tid >> 14) & 3;
    int l     = tid >> 16;
    int ln = lane & 15, quad = lane >> 4;
    int col = ghalf * 64 + ((ln >> 2) << 4) + (c << 2) + (ln & 3);
    int krow = (ks << 5) + (quad << 3) + j;
    const float* W = (mat == 0) ? Wq : (mat == 1) ? Wk : (mat == 2) ? Wv : Ws;
    float w = W[l * 16384 + krow * 128 + col];
    if (mat == 0) w *= QSCALE;
    Wbf[tid] = f2b(w);
}

// ---------------------------------------------------------------- CSR build
// XCD-partitioned (R9's single-pass regressed +32us: atomic lines ping-pong
// across the 8 non-coherent L2s; group=blockIdx&7 keeps each dst-range's
// atomics on one XCD).
__global__ __launch_bounds__(256) void hist_kernel(
    const int* __restrict__ dst, int* __restrict__ deg) {
    int group = blockIdx.x & 7;
    int gblk  = blockIdx.x >> 3;
    int nblk  = gridDim.x >> 3;
    int lo = group * DRANGE, hi = lo + DRANGE;
    for (int i = gblk * 256 + threadIdx.x; i < N_EDGES; i += nblk * 256) {
        int d = dst[i];
        if (d >= lo && d < hi) atomicAdd(&deg[d], 1);
    }
}

// exclusive scan of PADDED degrees ((deg+3)&~3) so each node's segment start
// is 4-aligned -> int4 source loads in the edge pass.
__global__ __launch_bounds__(1024) void scan_block_kernel(
    const int* __restrict__ deg, int* __restrict__ rowptr, int* __restrict__ sums) {
    __shared__ int tmp[1024];
    int t = threadIdx.x;
    int i = blockIdx.x * 1024 + t;
    int v = (i < N_NODES) ? ((deg[i] + 3) & ~3) : 0;
    tmp[t] = v;
    __syncthreads();
    for (int d = 1; d < 1024; d <<= 1) {
        int add = (t >= d) ? tmp[t - d] : 0;
        __syncthreads();
        tmp[t] += add;
        __syncthreads();
    }
    if (i < N_NODES) rowptr[i] = tmp[t] - v;
    if (t == 1023) sums[blockIdx.x] = tmp[1023];
}

// adds the cross-chunk prefix (inline wave-reduce over raw per-chunk sums),
// writes cursor, zeroes pad slots + 16 slack ints past the global padded end.
__global__ __launch_bounds__(256) void scan_add_kernel(
    int* __restrict__ rowptr, const int* __restrict__ sums,
    const int* __restrict__ deg,
    int* __restrict__ cursor, int* __restrict__ srcs) {
    __shared__ int base_s;
    int t = threadIdx.x;
    int limit = blockIdx.x >> 2;           // nodes here are in 1024-chunk (b>>2)
    if (t < 64) {
        int v = (t < limit) ? sums[t] : 0;           // limit <= 97
        int v2 = (t + 64 < limit) ? sums[t + 64] : 0;
        v += v2;
        for (int m = 1; m < 64; m <<= 1) v += __shfl_xor(v, m);
        if (t == 0) base_s = v;
    }
    __syncthreads();
    int base = base_s;
    int i = blockIdx.x * 256 + t;
    if (i < N_NODES) {
        int val = rowptr[i] + base;
        rowptr[i] = val;
        cursor[i] = val;
        int d = deg[i];
        int pad = ((d + 3) & ~3);
        for (int j = d; j < pad; ++j) srcs[val + j] = 0;
        if (i == N_NODES - 1) {
            int end = val + pad;
            for (int j = 0; j < 16; ++j) srcs[end + j] = 0;
        }
    }
}

// stores BYTE offsets of the source node's qkvs row (src*1024); XCD-partitioned
__global__ __launch_bounds__(256) void scatter_kernel(
    const int* __restrict__ src, const int* __restrict__ dst,
    int* __restrict__ cursor, int* __restrict__ srcs) {
    int group = blockIdx.x & 7;
    int gblk  = blockIdx.x >> 3;
    int nblk  = gridDim.x >> 3;
    int lo = group * DRANGE, hi = lo + DRANGE;
    for (int i = gblk * 256 + threadIdx.x; i < N_EDGES; i += nblk * 256) {
        int d = dst[i];
        if (d >= lo && d < hi) {
            int pos = atomicAdd(&cursor[d], 1);
            srcs[pos] = src[i] << 10;
        }
    }
}

// ---------------------------------------------------------------- QKVS GEMM (bf16 MFMA)
// Operand-swapped mfma(W, X) -> D[channel][node].  W in fragment-stream LDS
// layout [c][ks][lane][8]: linear staging + linear-in-lane ds_reads => zero
// bank conflicts.  Channel perm (wconv) makes lane outputs contiguous.
__global__ __launch_bounds__(512, 4) void gemm_qkvs_kernel(
    const void* __restrict__ Ap, int a_is_bf16,
    const unsigned short* __restrict__ Wbf,   // this layer: [mat][ghalf][c][ks][lane][8]
    const float* __restrict__ b0, const float* __restrict__ b1,
    const float* __restrict__ b2, const float* __restrict__ b3,
    unsigned short* __restrict__ out) {
    __shared__ unsigned short WL[2][8192];
    int t = threadIdx.x;
    int row0 = blockIdx.x * 128;
    int wr = t >> 6, lane = t & 63;
    int ln = lane & 15, quad = lane >> 4;
    int node = row0 + wr * 16 + ln;
    int nodeC = (node < N_NODES) ? node : (N_NODES - 1);

    bf16x8 aF[4];
    if (a_is_bf16) {
        const unsigned short* ar = (const unsigned short*)Ap + (size_t)nodeC * 128;
        #pragma unroll
        for (int ks = 0; ks < 4; ++ks)
            aF[ks] = *(const bf16x8*)&ar[ks * 32 + quad * 8];
    } else {
        const float* ar = (const float*)Ap + (size_t)nodeC * 128;
        #pragma unroll
        for (int ks = 0; ks < 4; ++ks) {
            float4 f0 = *(const float4*)&ar[ks * 32 + quad * 8];
            float4 f1 = *(const float4*)&ar[ks * 32 + quad * 8 + 4];
            union { unsigned u[4]; bf16x8 v; } cv;
            cv.u[0] = cvtpk(f0.x, f0.y);
            cv.u[1] = cvtpk(f0.z, f0.w);
            cv.u[2] = cvtpk(f1.x, f1.y);
            cv.u[3] = cvtpk(f1.z, f1.w);
            aF[ks] = cv.v;
        }
    }

    {
        const uint4* Wg4 = (const uint4*)Wbf;
        uint4 a = Wg4[t * 2], b = Wg4[t * 2 + 1];
        uint4* d4 = (uint4*)WL[0] + t * 2;
        d4[0] = a; d4[1] = b;
    }
    __syncthreads();

    bool ok = node < N_NODES;
    #pragma unroll
    for (int g = 0; g < 8; ++g) {
        int mat = g >> 1;
        int cur = g & 1;
        const float* bias = (mat == 0) ? b0 : (mat == 1) ? b1 : (mat == 2) ? b2 : b3;
        int cb = (g & 1) * 64;

        uint4 pfa, pfb;
        if (g < 7) {
            const uint4* Wg4 = (const uint4*)(Wbf + (size_t)(g + 1) * 8192);
            pfa = Wg4[t * 2]; pfb = Wg4[t * 2 + 1];
        }

        f32x4 acc[4];
        #pragma unroll
        for (int c = 0; c < 4; ++c) acc[c] = (f32x4){0.f, 0.f, 0.f, 0.f};
        #pragma unroll
        for (int ks = 0; ks < 4; ++ks) {
            #pragma unroll
            for (int c = 0; c < 4; ++c) {
                bf16x8 w = *(bf16x8*)&WL[cur][((c * 4 + ks) * 64 + lane) * 8];
                acc[c] = __builtin_amdgcn_mfma_f32_16x16x32_bf16(w, aF[ks], acc[c], 0, 0, 0);
            }
        }

        if (ok) {
            float s = (mat == 0) ? QSCALE : 1.0f;
            float v[16];
            #pragma unroll
            for (int c = 0; c < 4; ++c) {
                float4 bb = *(const float4*)&bias[cb + quad * 16 + c * 4];
                v[c * 4 + 0] = acc[c][0] + bb.x * s;
                v[c * 4 + 1] = acc[c][1] + bb.y * s;
                v[c * 4 + 2] = acc[c][2] + bb.z * s;
                v[c * 4 + 3] = acc[c][3] + bb.w * s;
            }
            unsigned pk[8];
            #pragma unroll
            for (int m = 0; m < 8; ++m) pk[m] = cvtpk(v[2 * m], v[2 * m + 1]);
            unsigned short* orow = out + (size_t)node * 512;
            if (mat == 0 || mat == 3) {
                int base = (mat == 0 ? 0 : 384) + cb + quad * 16;
                uint4 w0 = make_uint4(pk[0], pk[1], pk[2], pk[3]);
                uint4 w1 = make_uint4(pk[4], pk[5], pk[6], pk[7]);
                *(uint4*)&orow[base] = w0;
                *(uint4*)&orow[base + 8] = w1;
            } else {
                int boff = (mat == 2) ? 4 : 0;
                #pragma unroll
                for (int c = 0; c < 4; ++c) {
                    int pos = 128 + 8 * ((cb >> 2) + quad * 4 + c) + boff;
                    uint2 wd; wd.x = pk[2 * c]; wd.y = pk[2 * c + 1];
                    *(uint2*)&orow[pos] = wd;
                }
            }
        }

        if (g < 7) {
            uint4* d4 = (uint4*)WL[cur ^ 1] + t * 2;
            d4[0] = pfa; d4[1] = pfb;
        }
        __syncthreads();
    }
}

// ---------------------------------------------------------------- fused edge pass
// HALF-WAVE per edge; 8 edges/wave-iter; KV gathers DOUBLE-BUFFERED (next
// iter's 4 gathers issued before consuming current) and srcs kept TWO iters
// ahead, so gather issue never waits on an srcs load.  ~52 VGPR (<64 cliff).
#define EDGE(KV, ECOND) {                                            \
        float2 k01 = up2(KV.x), k23 = up2(KV.y);                     \
        float p = q01.x*k01.x + q01.y*k01.y + q23.x*k23.x + q23.y*k23.y; \
        p += __shfl_xor(p, 1);                                       \
        p += __shfl_xor(p, 2);                                       \
        p += __shfl_xor(p, 4);                                       \
        float e = (ECOND);                                           \
        float2 v01 = up2(KV.z), v23 = up2(KV.w);                     \
        a0 = fmaf(e, v01.x, a0); a1 = fmaf(e, v01.y, a1);            \
        a2 = fmaf(e, v23.x, a2); a3 = fmaf(e, v23.y, a3);            \
        dsum += e; }

__global__ __launch_bounds__(256) void edge_fused_kernel(
    const unsigned short* __restrict__ qkvs,
    const int* __restrict__ srcs, const int* __restrict__ rowptr,
    const int* __restrict__ deg,
    const float* __restrict__ gamma, const float* __restrict__ beta,
    unsigned short* __restrict__ hout) {
    int n = (blockIdx.x * 256 + threadIdx.x) >> 6;
    int lane = threadIdx.x & 63;
    if (n >= N_NODES) return;
    int half = lane >> 5, hl = lane & 31;
    const unsigned short* qrow = qkvs + (size_t)n * 512;
    uint2 qu = *(const uint2*)&qrow[4 * hl];
    float2 q01 = up2(qu.x), q23 = up2(qu.y);
    uint2 su = *(const uint2*)&qrow[384 + 4 * hl];
    float2 sk01 = up2(su.x), sk23 = up2(su.y);
    int e0 = rowptr[n];
    int rem = deg[n];
    const char* kbase = (const char*)qkvs + 256 + 16 * hl;
    const int* sb = srcs + e0 + 4 * half;   // 16B-aligned (e0 % 4 == 0)
    float a0 = 0.f, a1 = 0.f, a2 = 0.f, a3 = 0.f, dsum = 0.f;

    uint4 c0, c1, c2, c3;
    int4 on;
    if (rem >= 8) {
        int4 oc = *(const int4*)sb;
        c0 = *(const uint4*)(kbase + (unsigned)oc.x);
        c1 = *(const uint4*)(kbase + (unsigned)oc.y);
        c2 = *(const uint4*)(kbase + (unsigned)oc.z);
        c3 = *(const uint4*)(kbase + (unsigned)oc.w);
        if (rem >= 16) on = *(const int4*)(sb + 8);
    }
    while (rem >= 16) {
        // issue next iteration's gathers before consuming current
        uint4 n0 = *(const uint4*)(kbase + (unsigned)on.x);
        uint4 n1 = *(const uint4*)(kbase + (unsigned)on.y);
        uint4 n2 = *(const uint4*)(kbase + (unsigned)on.z);
        uint4 n3 = *(const uint4*)(kbase + (unsigned)on.w);
        // srcs two iters ahead; words may be junk but are only DEREFERENCED
        // next iteration when rem>=16 guarantees they are real data
        int4 of = *(const int4*)(sb + 16);
        EDGE(c0, EXP2(p));
        EDGE(c1, EXP2(p));
        EDGE(c2, EXP2(p));
        EDGE(c3, EXP2(p));
        c0 = n0; c1 = n1; c2 = n2; c3 = n3;
        on = of;
        sb += 8; rem -= 8;
    }
    if (rem >= 8) {                                  // last full block
        EDGE(c0, EXP2(p));
        EDGE(c1, EXP2(p));
        EDGE(c2, EXP2(p));
        EDGE(c3, EXP2(p));
        sb += 8; rem -= 8;
    }
    if (rem > 0) {                                   // one masked pass, rem in 1..7
        int4 ot = *(const int4*)sb;                  // pads+slack zeroed -> safe gather
        int tb = 4 * half;
        uint4 kv0 = *(const uint4*)(kbase + (unsigned)ot.x);
        uint4 kv1 = *(const uint4*)(kbase + (unsigned)ot.y);
        uint4 kv2 = *(const uint4*)(kbase + (unsigned)ot.z);
        uint4 kv3 = *(const uint4*)(kbase + (unsigned)ot.w);
        EDGE(kv0, (tb + 0 < rem) ? EXP2(p) : 0.f);
        EDGE(kv1, (tb + 1 < rem) ? EXP2(p) : 0.f);
        EDGE(kv2, (tb + 2 < rem) ? EXP2(p) : 0.f);
        EDGE(kv3, (tb + 3 < rem) ? EXP2(p) : 0.f);
    }

    // combine halves (lanes l and l+32 hold same channels, different edges)
    a0 += __shfl_xor(a0, 32); a1 += __shfl_xor(a1, 32);
    a2 += __shfl_xor(a2, 32); a3 += __shfl_xor(a3, 32);
    dsum += __shfl_xor(dsum, 32);
    float dinv = 1.0f / (dsum + 1e-16f);
    float o0 = a0 * dinv + sk01.x, o1 = a1 * dinv + sk01.y;
    float o2 = a2 * dinv + sk23.x, o3 = a3 * dinv + sk23.y;
    float sum = o0 + o1 + o2 + o3;
    for (int m = 1; m < 64; m <<= 1) sum += __shfl_xor(sum, m);
    float mu = sum * (1.0f / 256.0f);          // halves duplicated -> /256
    float d0 = o0 - mu, d1 = o1 - mu, d2 = o2 - mu, d3 = o3 - mu;
    float sq = d0 * d0 + d1 * d1 + d2 * d2 + d3 * d3;
    for (int m = 1; m < 64; m <<= 1) sq += __shfl_xor(sq, m);
    float rs = rsqrtf(sq * (1.0f / 256.0f) + 1e-5f);
    if (half == 0) {
        float4 g4 = *(const float4*)&gamma[4 * hl];
        float4 b4 = *(const float4*)&beta[4 * hl];
        float r0 = fmaxf(d0 * rs * g4.x + b4.x, 0.f);
        float r1 = fmaxf(d1 * rs * g4.y + b4.y, 0.f);
        float r2 = fmaxf(d2 * rs * g4.z + b4.z, 0.f);
        float r3 = fmaxf(d3 * rs * g4.w + b4.w, 0.f);
        uint2 w;
        w.x = cvtpk(r0, r1);
        w.y = cvtpk(r2, r3);
        *(uint2*)&hout[(size_t)n * 128 + 4 * hl] = w;
    }
}

// ---------------------------------------------------------------- classifier (h is bf16)
__global__ __launch_bounds__(256) void out_gemm_kernel(
    const unsigned short* __restrict__ h, const float* __restrict__ Wout,
    const float* __restrict__ bout, float* __restrict__ out) {
    int wv = __builtin_amdgcn_readfirstlane((int)(threadIdx.x >> 6)); // 0..3
    int l = threadIdx.x & 63;
    int n = blockIdx.x * 64 + l;
    int jb = wv * 10;
    int nc = (n < N_NODES) ? n : (N_NODES - 1);
    const unsigned short* hrow = h + (size_t)nc * 128;
    uint4 hp[16];
    #pragma unroll
    for (int i = 0; i < 16; ++i) hp[i] = *(const uint4*)&hrow[i * 8];
    float acc[10];
    #pragma unroll
    for (int j = 0; j < 10; ++j) acc[j] = bout[jb + j];
    #pragma unroll
    for (int i = 0; i < 16; ++i) {   // channel group 8i..8i+7
        float2 c01 = up2(hp[i].x), c23 = up2(hp[i].y);
        float2 c45 = up2(hp[i].z), c67 = up2(hp[i].w);
        float hc0 = c01.x, hc1 = c01.y, hc2 = c23.x, hc3 = c23.y;
        float hc4 = c45.x, hc5 = c45.y, hc6 = c67.x, hc7 = c67.y;
        #pragma unroll
        for (int j = 0; j < 10; ++j) {
            const float* wk = Wout + (i * 8) * NCLS_ + jb + j;
            acc[j] = fmaf(hc0, wk[0 * NCLS_], acc[j]);
            acc[j] = fmaf(hc1, wk[1 * NCLS_], acc[j]);
            acc[j] = fmaf(hc2, wk[2 * NCLS_], acc[j]);
            acc[j] = fmaf(hc3, wk[3 * NCLS_], acc[j]);
            acc[j] = fmaf(hc4, wk[4 * NCLS_], acc[j]);
            acc[j] = fmaf(hc5, wk[5 * NCLS_], acc[j]);
            acc[j] = fmaf(hc6, wk[6 * NCLS_], acc[j]);
            acc[j] = fmaf(hc7, wk[7 * NCLS_], acc[j]);
        }
    }
    if (n < N_NODES) {
        #pragma unroll
        for (int j = 0; j < 10; ++j) out[(size_t)n * NCLS_ + jb + j] = acc[j];
    }
}

// ---------------------------------------------------------------- launch
extern "C" void kernel_launch(void* const* d_in, const int* in_sizes, int n_in,
                              void* d_out, int out_size, void* d_ws, size_t ws_size,
                              hipStream_t stream) {
    const float* x    = (const float*)d_in[0];
    const int*   ei   = (const int*)d_in[1];
    const int*   src  = ei;
    const int*   dst  = ei + N_EDGES;
    const float* Wq   = (const float*)d_in[2];
    const float* bq   = (const float*)d_in[3];
    const float* Wk   = (const float*)d_in[4];
    const float* bk   = (const float*)d_in[5];
    const float* Wv   = (const float*)d_in[6];
    const float* bv   = (const float*)d_in[7];
    const float* Wsk  = (const float*)d_in[8];
    const float* bsk  = (const float*)d_in[9];
    const float* gmm  = (const float*)d_in[10];
    const float* bta  = (const float*)d_in[11];
    const float* Wout = (const float*)d_in[12];
    const float* bout = (const float*)d_in[13];
    float* outp = (float*)d_out;

    char* p = (char*)d_ws;
    auto carve = [&](size_t bytes) {
        char* r = p;
        p += (bytes + 255) & ~(size_t)255;
        return r;
    };
    unsigned short* qkvs = (unsigned short*)carve((size_t)N_NODES * 512 * 2);
    unsigned short* h    = (unsigned short*)carve((size_t)N_NODES * 128 * 2);
    unsigned short* Wbf  = (unsigned short*)carve((size_t)131072 * 2);
    int* deg     = (int*)carve((size_t)N_NODES * 4);
    int* rowptr  = (int*)carve((size_t)(N_NODES + 1) * 4);
    int* cursor  = (int*)carve((size_t)N_NODES * 4);
    int* srcs    = (int*)carve((size_t)SRCS_PAD * 4);
    int* sums    = (int*)carve((size_t)NSCAN_BLOCKS * 4);

    wconv_zero_kernel<<<512 + (N_NODES + 255) / 256, 256, 0, stream>>>(
        Wq, Wk, Wv, Wsk, Wbf, deg);
    hist_kernel<<<2048, 256, 0, stream>>>(dst, deg);
    scan_block_kernel<<<NSCAN_BLOCKS, 1024, 0, stream>>>(deg, rowptr, sums);
    scan_add_kernel<<<(N_NODES + 255) / 256, 256, 0, stream>>>(rowptr, sums, deg, cursor, srcs);
    scatter_kernel<<<2048, 256, 0, stream>>>(src, dst, cursor, srcs);

    for (int l = 0; l < 2; ++l) {
        const void* hin = l ? (const void*)h : (const void*)x;
        gemm_qkvs_kernel<<<(N_NODES + 127) / 128, 512, 0, stream>>>(
            hin, l, Wbf + (size_t)l * 65536,
            bq + l * 128, bk + l * 128, bv + l * 128, bsk + l * 128, qkvs);
        edge_fused_kernel<<<(N_NODES + 3) / 4, 256, 0, stream>>>(
            qkvs, srcs, rowptr, deg, gmm + l * 128, bta + l * 128, h);
    }
    out_gemm_kernel<<<(N_NODES + 63) / 64, 256, 0, stream>>>(h, Wout, bout, outp);
}